// Round 4
// baseline (5262.582 us; speedup 1.0000x reference)
//
#include <hip/hip_runtime.h>
#include <hip/hip_bf16.h>
#include <stdint.h>

typedef __attribute__((ext_vector_type(4))) float f32x4;
typedef __attribute__((ext_vector_type(2))) float f32x2;
typedef __attribute__((ext_vector_type(8))) short s16x8;
typedef __attribute__((ext_vector_type(4))) uint32_t u32x4;
typedef __hip_bfloat16 bf16;

#define NBLK 128   // recurrence blocks; each owns 4 j-columns (16 gate-cols)

__device__ __forceinline__ float sigf(float x){ return 1.f/(1.f+__expf(-x)); }
__device__ __forceinline__ float tanh_f(float x){ float e=__expf(2.f*x); return (e-1.f)/(e+1.f); }

__device__ __forceinline__ void st_f32_agent(float* p, float v){
  __hip_atomic_store(p, v, __ATOMIC_RELAXED, __HIP_MEMORY_SCOPE_AGENT);
}
__device__ __forceinline__ uint64_t ld_u64_agent(const uint64_t* p){
  return __hip_atomic_load(p, __ATOMIC_RELAXED, __HIP_MEMORY_SCOPE_AGENT);
}
__device__ __forceinline__ void st_u32_agent(uint32_t* p, uint32_t v){
  __hip_atomic_store(p, v, __ATOMIC_RELAXED, __HIP_MEMORY_SCOPE_AGENT);
}

// Poll: 128 flags, each padded to a 128B line. Lane i watches lines i and i+64.
__device__ __forceinline__ void poll_flags128(const uint32_t* flags, uint32_t tgt){
  const uint64_t* f64 = (const uint64_t*)flags;
  int lane = threadIdx.x & 63;
  uint32_t spins = 0;
  for(;;){
    uint64_t v0 = ld_u64_agent(&f64[lane*16]);        // block lane
    uint64_t v1 = ld_u64_agent(&f64[(lane+64)*16]);   // block lane+64
    bool ok = ((uint32_t)v0 >= tgt) && ((uint32_t)v1 >= tgt);
    if (__all(ok)) break;
    __builtin_amdgcn_s_sleep(1);
    if (++spins > (1u<<18)) break;  // broken protocol -> visible failure
  }
}

// ---------------- convert f32 -> bf16 ----------------
__global__ __launch_bounds__(256) void k_convert(const float* __restrict__ in, bf16* __restrict__ outp, int n){
  int i = (blockIdx.x*256 + threadIdx.x)*4;
  if (i >= n) return;
  f32x4 v = *(const f32x4*)&in[i];
  alignas(8) bf16 tmp[4] = {__float2bfloat16(v.x), __float2bfloat16(v.y), __float2bfloat16(v.z), __float2bfloat16(v.w)};
  *(uint64_t*)&outp[i] = *(const uint64_t*)tmp;
}

// ---------------- encoder embedding gather -> Xe[t*16+b][e] (bf16) ----------------
__global__ __launch_bounds__(256) void k_embed(const int* __restrict__ enc_in, const float* __restrict__ emb,
                                               bf16* __restrict__ Xe){
  int i = blockIdx.x*256 + threadIdx.x;
  int o = i*4;
  int row = o >> 9, e = o & 511;
  int t = row >> 4, b = row & 15;
  int tok = enc_in[b*512 + t];
  f32x4 v = *(const f32x4*)&emb[(size_t)tok*512 + e];
  alignas(8) bf16 tmp[4] = {__float2bfloat16(v.x), __float2bfloat16(v.y), __float2bfloat16(v.z), __float2bfloat16(v.w)};
  *(uint64_t*)&Xe[o] = *(const uint64_t*)tmp;
}

// ---------------- bf16 MFMA GEMM: C[M][N] = A[M][K] * B[N][K]^T + bias ----------------
template<int OUT_BF16>
__global__ __launch_bounds__(256) void k_gemm(
    const bf16* __restrict__ A, const bf16* __restrict__ Bm,
    const float* __restrict__ bias1, const float* __restrict__ bias2,
    void* __restrict__ Cp, int M, int N, int K)
{
  __shared__ bf16 Al[128*32];
  __shared__ bf16 Bl[128*32];
  const int tid = threadIdx.x;
  const int n0 = blockIdx.x*128, m0 = blockIdx.y*128;
  const int wv = tid >> 6, lane = tid & 63;
  const int wr = (wv >> 1)*64, wc = (wv & 1)*64;
  const int lrow = lane & 15, lk = (lane >> 4)*8;
  const int r1 = tid >> 2, kq = (tid & 3)*8;

  f32x4 acc[4][4];
  #pragma unroll
  for (int i=0;i<4;++i)
    #pragma unroll
    for (int j=0;j<4;++j) { f32x4 z = {0.f,0.f,0.f,0.f}; acc[i][j] = z; }

  const bf16* pa0 = &A[(size_t)(m0 + r1)*K + kq];
  const bf16* pa1 = &A[(size_t)(m0 + 64 + r1)*K + kq];
  const bf16* pb0 = &Bm[(size_t)(n0 + r1)*K + kq];
  const bf16* pb1 = &Bm[(size_t)(n0 + 64 + r1)*K + kq];

  u32x4 a0 = *(const u32x4*)pa0, a1 = *(const u32x4*)pa1;
  u32x4 b0 = *(const u32x4*)pb0, b1 = *(const u32x4*)pb1;

  const int nk = K >> 5;
  for (int kt = 0; kt < nk; ++kt) {
    __syncthreads();
    *(u32x4*)&Al[r1*32 + kq]        = a0;
    *(u32x4*)&Al[(64 + r1)*32 + kq] = a1;
    *(u32x4*)&Bl[r1*32 + kq]        = b0;
    *(u32x4*)&Bl[(64 + r1)*32 + kq] = b1;
    __syncthreads();
    if (kt + 1 < nk) {
      int off = (kt+1)*32;
      a0 = *(const u32x4*)(pa0 + off); a1 = *(const u32x4*)(pa1 + off);
      b0 = *(const u32x4*)(pb0 + off); b1 = *(const u32x4*)(pb1 + off);
    }
    s16x8 af[4], bfr[4];
    #pragma unroll
    for (int mi=0;mi<4;++mi) af[mi]  = *(const s16x8*)&Al[(wr + mi*16 + lrow)*32 + lk];
    #pragma unroll
    for (int ni=0;ni<4;++ni) bfr[ni] = *(const s16x8*)&Bl[(wc + ni*16 + lrow)*32 + lk];
    #pragma unroll
    for (int mi=0;mi<4;++mi)
      #pragma unroll
      for (int ni=0;ni<4;++ni)
        acc[mi][ni] = __builtin_amdgcn_mfma_f32_16x16x32_bf16(af[mi], bfr[ni], acc[mi][ni], 0, 0, 0);
  }
  const int crow = (lane >> 4)*4;
  #pragma unroll
  for (int mi=0;mi<4;++mi) {
    #pragma unroll
    for (int ni=0;ni<4;++ni) {
      int cc = n0 + wc + ni*16 + lrow;
      float badd = (bias1 ? bias1[cc] : 0.f) + (bias2 ? bias2[cc] : 0.f);
      #pragma unroll
      for (int q=0;q<4;++q) {
        int rr = m0 + wr + mi*16 + crow + q;
        float v = acc[mi][ni][q] + badd;
        if (OUT_BF16) ((bf16*)Cp)[(size_t)rr*N + cc] = __float2bfloat16(v);
        else          ((float*)Cp)[(size_t)rr*N + cc] = v;
      }
    }
  }
}

// ---------------- encoder recurrence: 512 sequential steps ----------------
// 128 blocks x 256 thr (4 waves), 1 block/CU. Block owns 4 j's (16 gate-cols).
// Thread = (bgrp: 4 batches [wave], g: gate, ksl: 32-wide k-slice). Each thread
// holds 4 columns' weights in registers (4x8 f32x4) -> each h f32x4 feeds 16 FMA.
// Reduction is in-wave (shfl over 16 ksl lanes). Exchange: h_ex[2][128][64]
// exclusive 256B lines; one padded flag line per block.
__global__ __launch_bounds__(256, 1) void k_encoder(
    const bf16* __restrict__ GXe, const float* __restrict__ w_hh,
    float* __restrict__ h_ex, float* __restrict__ c_glob,
    float* __restrict__ enc_out, uint32_t* __restrict__ flags)
{
  const int tid = threadIdx.x, bid = blockIdx.x;
  const int ksl = tid & 15;          // k-slice (32 floats)
  const int g   = (tid >> 4) & 3;    // gate
  const int bgrp= tid >> 6;          // wave index = 4-batch group
  const int wvi = tid >> 6;

  __shared__ float h_lds[16*520];
  __shared__ float gate_lds[16*20];
  __shared__ float h_out_l[64];

  // weights: 4 jl columns x 32 k, bank-rotated k-quad order (matched at use)
  f32x4 wreg[4][8];
  #pragma unroll
  for (int jl = 0; jl < 4; ++jl) {
    const float* wrow = &w_hh[(size_t)(g*512 + bid*4 + jl)*512 + ksl*32];
    #pragma unroll
    for (int i = 0; i < 8; ++i) {
      int kk = (i + ksl) & 7;
      wreg[jl][i] = *(const f32x4*)&wrow[kk*4];
    }
  }
  float c_reg = 0.f;                                  // producers tid<64
  const int pb = tid & 15, pjl = tid >> 4;            // producer mapping (wave 0)

  for (int t = 0; t < 512; ++t) {
    // prefetch GXe for finalizer lanes (4 contiguous bf16 per batch = u64)
    uint64_t gx[4];
    if (ksl == 0) {
      #pragma unroll
      for (int bi = 0; bi < 4; ++bi)
        gx[bi] = *(const uint64_t*)&GXe[(size_t)(t*16 + bgrp*4 + bi)*2048 + g*512 + bid*4];
    }
    float acc[4][4];
    #pragma unroll
    for (int bi=0;bi<4;++bi)
      #pragma unroll
      for (int jl=0;jl<4;++jl) acc[bi][jl] = 0.f;

    if (t > 0) {
      if (wvi == 0) poll_flags128(flags, (uint32_t)t);
      __syncthreads();                                 // (A)
      const uint64_t* hg = (const uint64_t*)(h_ex + (t & 1)*8192);
      #pragma unroll
      for (int q = 0; q < 16; ++q) {
        int u = q*256 + tid;                           // u64 idx 0..4095
        uint64_t v = ld_u64_agent(&hg[u]);
        int bid2 = u >> 5, rem = u & 31, bb = rem >> 1, jh = rem & 1;
        *(uint64_t*)&h_lds[bb*520 + bid2*4 + jh*2] = v;
      }
      __syncthreads();                                 // (B)
      #pragma unroll
      for (int bi = 0; bi < 4; ++bi) {
        const float* hrow = &h_lds[(bgrp*4 + bi)*520 + ksl*32];
        #pragma unroll
        for (int i = 0; i < 8; ++i) {
          int kk = (i + ksl) & 7;
          f32x4 hv = *(const f32x4*)&hrow[kk*4];
          #pragma unroll
          for (int jl = 0; jl < 4; ++jl) {
            acc[bi][jl] = __fmaf_rn(hv.x, wreg[jl][i].x, acc[bi][jl]);
            acc[bi][jl] = __fmaf_rn(hv.y, wreg[jl][i].y, acc[bi][jl]);
            acc[bi][jl] = __fmaf_rn(hv.z, wreg[jl][i].z, acc[bi][jl]);
            acc[bi][jl] = __fmaf_rn(hv.w, wreg[jl][i].w, acc[bi][jl]);
          }
        }
      }
      // in-wave reduce over 16 ksl lanes
      #pragma unroll
      for (int bi = 0; bi < 4; ++bi)
        #pragma unroll
        for (int jl = 0; jl < 4; ++jl) {
          float v = acc[bi][jl];
          v += __shfl_xor(v, 1);
          v += __shfl_xor(v, 2);
          v += __shfl_xor(v, 4);
          v += __shfl_xor(v, 8);
          acc[bi][jl] = v;
        }
    }
    if (ksl == 0) {
      #pragma unroll
      for (int bi = 0; bi < 4; ++bi) {
        #pragma unroll
        for (int jl = 0; jl < 4; ++jl) {
          uint32_t hbits = ((uint32_t)(gx[bi] >> (16*jl)) & 0xffffu) << 16;
          float gxf = __uint_as_float(hbits);
          gate_lds[(bgrp*4 + bi)*20 + g*4 + jl] = acc[bi][jl] + gxf;
        }
      }
    }
    __syncthreads();                                   // (D)
    if (tid < 64) {
      float gi = gate_lds[pb*20 +      pjl];
      float gf = gate_lds[pb*20 +  4 + pjl];
      float gg = gate_lds[pb*20 +  8 + pjl];
      float go = gate_lds[pb*20 + 12 + pjl];
      float cn = sigf(gf)*c_reg + sigf(gi)*tanh_f(gg);
      float hn = sigf(go)*tanh_f(cn);
      c_reg = cn;
      st_f32_agent(&h_ex[((t+1) & 1)*8192 + bid*64 + pb*4 + pjl], hn);
      h_out_l[tid] = hn;
      asm volatile("s_waitcnt vmcnt(0)" ::: "memory"); // covers only wave 0's h stores
      if (tid == 0) st_u32_agent(&flags[bid*32], (uint32_t)(t + 1));
    }
    __syncthreads();                                   // (E)
    if (tid >= 64 && tid < 128) {
      int ob = (tid - 64) & 15, ojl = (tid - 64) >> 4;
      enc_out[((size_t)ob*512 + t)*512 + bid*4 + ojl] = h_out_l[tid - 64];
    }
  }
  if (tid < 64) c_glob[pb*512 + bid*4 + pjl] = c_reg;
}

// ---------------- gates for decoder step 0 (hT read from permuted h_ex[0]) ----------------
__global__ __launch_bounds__(128) void k_gates0(
    const int* __restrict__ dec_in, const float* __restrict__ emb,
    const float* __restrict__ hT,   // h_ex[0]: [128][64] = [k>>2][b*4 + (k&3)]
    const float* __restrict__ w_ih, const float* __restrict__ w_hh,
    const float* __restrict__ b_ih, const float* __restrict__ b_hh,
    float* __restrict__ g0)
{
  int gt = blockIdx.x*128 + threadIdx.x;
  int b = gt & 15, col = gt >> 4;
  const float* x0 = &emb[(size_t)dec_in[b*128] * 512];
  const float* wi = &w_ih[(size_t)col*512];
  const float* wh = &w_hh[(size_t)col*512];
  float s0=0.f, s1=0.f;
  for (int k4 = 0; k4 < 128; ++k4) {
    f32x4 hv  = *(const f32x4*)&hT[k4*64 + b*4];
    f32x4 xv  = *(const f32x4*)&x0[k4*4];
    f32x4 wiv = *(const f32x4*)&wi[k4*4];
    f32x4 whv = *(const f32x4*)&wh[k4*4];
    s0 += xv.x*wiv.x + xv.y*wiv.y + xv.z*wiv.z + xv.w*wiv.w;
    s1 += hv.x*whv.x + hv.y*whv.y + hv.z*whv.z + hv.w*whv.w;
  }
  g0[b*2048 + col] = s0 + s1 + b_ih[col] + b_hh[col];
}

// ---------------- decoder recurrence: 128 sequential steps (x_t == h_t for t>=1) ----------------
__global__ __launch_bounds__(256, 1) void k_decoder(
    const float* __restrict__ w_ih, const float* __restrict__ w_hh,
    const float* __restrict__ b_ih, const float* __restrict__ b_hh,
    const float* __restrict__ gates0,
    float* __restrict__ h_ex, const float* __restrict__ c_glob,
    float* __restrict__ dec_h, bf16* __restrict__ dec_out,
    uint32_t* __restrict__ flags)
{
  const int tid = threadIdx.x, bid = blockIdx.x;
  const int ksl = tid & 15;
  const int g   = (tid >> 4) & 3;
  const int bgrp= tid >> 6;
  const int wvi = tid >> 6;

  __shared__ float h_lds[16*520];
  __shared__ float gate_lds[16*20];
  __shared__ float h_out_l[64];

  f32x4 wreg[4][8];
  float bias_j[4];
  #pragma unroll
  for (int jl = 0; jl < 4; ++jl) {
    int colg = g*512 + bid*4 + jl;
    bias_j[jl] = b_ih[colg] + b_hh[colg];
    const float* wrowa = &w_ih[(size_t)colg*512 + ksl*32];
    const float* wrowb = &w_hh[(size_t)colg*512 + ksl*32];
    #pragma unroll
    for (int i = 0; i < 8; ++i) {
      int kk = (i + ksl) & 7;
      f32x4 wa = *(const f32x4*)&wrowa[kk*4];
      f32x4 wb = *(const f32x4*)&wrowb[kk*4];
      wreg[jl][i] = wa + wb;
    }
  }
  const int pb = tid & 15, pjl = tid >> 4;
  float c_reg = 0.f;
  if (tid < 64) c_reg = c_glob[pb*512 + bid*4 + pjl];

  for (int t = 0; t < 128; ++t) {
    float acc[4][4];
    #pragma unroll
    for (int bi=0;bi<4;++bi)
      #pragma unroll
      for (int jl=0;jl<4;++jl) acc[bi][jl] = 0.f;

    if (t > 0) {
      if (wvi == 0) poll_flags128(flags, (uint32_t)t);
      __syncthreads();                                 // (A)
      const uint64_t* hg = (const uint64_t*)(h_ex + (t & 1)*8192);
      #pragma unroll
      for (int q = 0; q < 16; ++q) {
        int u = q*256 + tid;
        uint64_t v = ld_u64_agent(&hg[u]);
        int bid2 = u >> 5, rem = u & 31, bb = rem >> 1, jh = rem & 1;
        *(uint64_t*)&h_lds[bb*520 + bid2*4 + jh*2] = v;
      }
      __syncthreads();                                 // (B)
      #pragma unroll
      for (int bi = 0; bi < 4; ++bi) {
        const float* hrow = &h_lds[(bgrp*4 + bi)*520 + ksl*32];
        #pragma unroll
        for (int i = 0; i < 8; ++i) {
          int kk = (i + ksl) & 7;
          f32x4 hv = *(const f32x4*)&hrow[kk*4];
          #pragma unroll
          for (int jl = 0; jl < 4; ++jl) {
            acc[bi][jl] = __fmaf_rn(hv.x, wreg[jl][i].x, acc[bi][jl]);
            acc[bi][jl] = __fmaf_rn(hv.y, wreg[jl][i].y, acc[bi][jl]);
            acc[bi][jl] = __fmaf_rn(hv.z, wreg[jl][i].z, acc[bi][jl]);
            acc[bi][jl] = __fmaf_rn(hv.w, wreg[jl][i].w, acc[bi][jl]);
          }
        }
      }
      #pragma unroll
      for (int bi = 0; bi < 4; ++bi)
        #pragma unroll
        for (int jl = 0; jl < 4; ++jl) {
          float v = acc[bi][jl];
          v += __shfl_xor(v, 1);
          v += __shfl_xor(v, 2);
          v += __shfl_xor(v, 4);
          v += __shfl_xor(v, 8);
          acc[bi][jl] = v;
        }
    }
    if (ksl == 0) {
      if (t == 0) {
        #pragma unroll
        for (int bi = 0; bi < 4; ++bi) {
          f32x4 gv = *(const f32x4*)&gates0[(size_t)(bgrp*4 + bi)*2048 + g*512 + bid*4];
          gate_lds[(bgrp*4 + bi)*20 + g*4 + 0] = gv.x;
          gate_lds[(bgrp*4 + bi)*20 + g*4 + 1] = gv.y;
          gate_lds[(bgrp*4 + bi)*20 + g*4 + 2] = gv.z;
          gate_lds[(bgrp*4 + bi)*20 + g*4 + 3] = gv.w;
        }
      } else {
        #pragma unroll
        for (int bi = 0; bi < 4; ++bi)
          #pragma unroll
          for (int jl = 0; jl < 4; ++jl)
            gate_lds[(bgrp*4 + bi)*20 + g*4 + jl] = acc[bi][jl] + bias_j[jl];
      }
    }
    __syncthreads();                                   // (D)
    if (tid < 64) {
      float gi = gate_lds[pb*20 +      pjl];
      float gf = gate_lds[pb*20 +  4 + pjl];
      float gg = gate_lds[pb*20 +  8 + pjl];
      float go = gate_lds[pb*20 + 12 + pjl];
      float cn = sigf(gf)*c_reg + sigf(gi)*tanh_f(gg);
      float hn = sigf(go)*tanh_f(cn);
      c_reg = cn;
      st_f32_agent(&h_ex[((t+1) & 1)*8192 + bid*64 + pb*4 + pjl], hn);
      h_out_l[tid] = hn;
      asm volatile("s_waitcnt vmcnt(0)" ::: "memory");
      if (tid == 0) st_u32_agent(&flags[bid*32], (uint32_t)(t + 1));
    }
    __syncthreads();                                   // (E)
    if (tid >= 64 && tid < 128) {
      int ob = (tid - 64) & 15, ojl = (tid - 64) >> 4;
      float hn = h_out_l[tid - 64];
      int jgl = bid*4 + ojl;
      dec_h[((size_t)t*16 + ob)*512 + jgl] = hn;
      dec_out[((size_t)(ob*128 + t))*1024 + jgl] = __float2bfloat16(hn);
    }
  }
}

// ---------------- batched attention over all (t,b) ----------------
__global__ __launch_bounds__(256) void k_attn(
    const float* __restrict__ dec_h, const float* __restrict__ enc_out,
    bf16* __restrict__ dOut)
{
  const int tid = threadIdx.x, bid = blockIdx.x;
  const int b = bid >> 3, t0 = (bid & 7)*16;
  __shared__ float h16[16*512];
  __shared__ float sc[16*512];
  #pragma unroll
  for (int q = 0; q < 8; ++q) {
    int fi = q*256 + tid;
    int tt = fi >> 7, e4 = (fi & 127)*4;
    *(f32x4*)&h16[tt*512 + e4] = *(const f32x4*)&dec_h[((size_t)(t0 + tt)*16 + b)*512 + e4];
  }
  __syncthreads();
  const float* encb = &enc_out[(size_t)b*512*512];
  for (int si = 0; si < 2; ++si) {
    int s = si*256 + tid;
    float a[16];
    #pragma unroll
    for (int tt=0;tt<16;++tt) a[tt]=0.f;
    for (int e4 = 0; e4 < 512; e4 += 4) {
      f32x4 ev = *(const f32x4*)&encb[(size_t)s*512 + e4];
      #pragma unroll
      for (int tt = 0; tt < 16; ++tt) {
        f32x4 hv = *(const f32x4*)&h16[tt*512 + e4];
        a[tt] += ev.x*hv.x + ev.y*hv.y + ev.z*hv.z + ev.w*hv.w;
      }
    }
    #pragma unroll
    for (int tt=0;tt<16;++tt) sc[tt*512 + s] = a[tt];
  }
  __syncthreads();
  {
    int wv = tid >> 6, lane = tid & 63;
    #pragma unroll
    for (int u = 0; u < 4; ++u) {
      int tt = wv*4 + u;
      float x[8];
      float m = -1e30f;
      #pragma unroll
      for (int i=0;i<8;++i){ x[i] = sc[tt*512 + i*64 + lane]; m = fmaxf(m, x[i]); }
      #pragma unroll
      for (int off=1; off<64; off<<=1) m = fmaxf(m, __shfl_xor(m, off));
      float sum = 0.f;
      #pragma unroll
      for (int i=0;i<8;++i){ x[i] = __expf(x[i]-m); sum += x[i]; }
      #pragma unroll
      for (int off=1; off<64; off<<=1) sum += __shfl_xor(sum, off);
      float inv = 1.f/sum;
      #pragma unroll
      for (int i=0;i<8;++i) sc[tt*512 + i*64 + lane] = x[i]*inv;
    }
  }
  __syncthreads();
  {
    int e0 = tid*2;
    float cx[16], cy[16];
    #pragma unroll
    for (int tt=0;tt<16;++tt){ cx[tt]=0.f; cy[tt]=0.f; }
    for (int s = 0; s < 512; ++s) {
      f32x2 ev = *(const f32x2*)&encb[(size_t)s*512 + e0];
      #pragma unroll
      for (int tt = 0; tt < 16; ++tt) {
        float aw = sc[tt*512 + s];
        cx[tt] += aw*ev.x; cy[tt] += aw*ev.y;
      }
    }
    #pragma unroll
    for (int tt = 0; tt < 16; ++tt) {
      size_t rowo = ((size_t)(b*128 + t0 + tt))*1024 + 512 + e0;
      alignas(4) bf16 tmp[2] = {__float2bfloat16(cx[tt]), __float2bfloat16(cy[tt])};
      *(uint32_t*)&dOut[rowo] = *(const uint32_t*)tmp;
    }
  }
}

// ---------------- host ----------------
extern "C" void kernel_launch(void* const* d_in, const int* in_sizes, int n_in,
                              void* d_out, int out_size, void* d_ws, size_t ws_size,
                              hipStream_t stream)
{
  const int*   enc_in = (const int*)d_in[0];
  const int*   dec_in = (const int*)d_in[1];
  const float* emb    = (const float*)d_in[2];
  const float* w_ih_e = (const float*)d_in[3];
  const float* w_hh_e = (const float*)d_in[4];
  const float* b_ih_e = (const float*)d_in[5];
  const float* b_hh_e = (const float*)d_in[6];
  const float* w_ih_d = (const float*)d_in[7];
  const float* w_hh_d = (const float*)d_in[8];
  const float* b_ih_d = (const float*)d_in[9];
  const float* b_hh_d = (const float*)d_in[10];
  const float* w_proj = (const float*)d_in[11];
  const float* b_proj = (const float*)d_in[12];
  float* out = (float*)d_out;

  char* ws = (char*)d_ws;
  size_t off = 0;
  auto alloc = [&](size_t bytes)->void* { void* p = ws + off; off += (bytes + 255) & ~(size_t)255; return p; };
  bf16*  Wp      = (bf16*)alloc(32000ull*1024*2);
  bf16*  Xe      = (bf16*)alloc(8192ull*512*2);
  bf16*  Wie     = (bf16*)alloc(2048ull*512*2);
  bf16*  GXe     = (bf16*)alloc(8192ull*2048*2);
  float* enc_out = (float*)alloc(16ull*512*512*4);
  float* dec_h   = (float*)alloc(128ull*16*512*4);
  bf16*  dOutB   = (bf16*)alloc(2048ull*1024*2);
  float* h_ex    = (float*)alloc(2*128*64*4);       // [2][128 blocks][64] exclusive lines
  float* c_g     = (float*)alloc(16*512*4);
  float* g0      = (float*)alloc(16*2048*4);
  uint32_t* flagsE = (uint32_t*)alloc(128*128);     // one 128B line per block
  uint32_t* flagsD = (uint32_t*)alloc(128*128);
  if (off > ws_size) return;  // workspace too small -> fail validation loudly

  (void)hipMemsetAsync(flagsE, 0, 128*128, stream);
  (void)hipMemsetAsync(flagsD, 0, 128*128, stream);

  k_convert<<<32000, 256, 0, stream>>>(w_proj, Wp, 32768000);
  k_convert<<<1024, 256, 0, stream>>>(w_ih_e, Wie, 1048576);
  k_embed<<<4096, 256, 0, stream>>>(enc_in, emb, Xe);
  // encoder input gates for all timesteps: GXe = Xe @ w_ih_e^T + (b_ih_e + b_hh_e)
  k_gemm<1><<<dim3(16, 64), 256, 0, stream>>>(Xe, Wie, b_ih_e, b_hh_e, GXe, 8192, 2048, 512);
  k_encoder<<<NBLK, 256, 0, stream>>>(GXe, w_hh_e, h_ex, c_g, enc_out, flagsE);
  // final encoder h lands in h_ex[0] (t=511 writes buf (512&1)=0), permuted layout
  k_gates0<<<256, 128, 0, stream>>>(dec_in, emb, h_ex, w_ih_d, w_hh_d, b_ih_d, b_hh_d, g0);
  k_decoder<<<NBLK, 256, 0, stream>>>(w_ih_d, w_hh_d, b_ih_d, b_hh_d, g0, h_ex, c_g, dec_h, dOutB, flagsD);
  k_attn<<<128, 256, 0, stream>>>(dec_h, enc_out, dOutB);
  // logits = dec_out @ w_proj^T + b_proj
  k_gemm<0><<<dim3(250, 16), 256, 0, stream>>>(dOutB, Wp, b_proj, nullptr, out, 2048, 32000, 1024);
}

// Round 6
// 4901.087 us; speedup vs baseline: 1.0738x; 1.0738x over previous
//
#include <hip/hip_runtime.h>
#include <hip/hip_bf16.h>
#include <stdint.h>

typedef __attribute__((ext_vector_type(4))) float f32x4;
typedef __attribute__((ext_vector_type(2))) float f32x2;
typedef __attribute__((ext_vector_type(8))) short s16x8;
typedef __attribute__((ext_vector_type(4))) uint32_t u32x4;
typedef __hip_bfloat16 bf16;
typedef unsigned long long u64;

#define NBLK 128   // recurrence blocks; each owns 4 j-columns (16 gate-cols)

__device__ __forceinline__ float sigf(float x){ return 1.f/(1.f+__expf(-x)); }
__device__ __forceinline__ float tanh_f(float x){ float e=__expf(2.f*x); return (e-1.f)/(e+1.f); }

__device__ __forceinline__ u64 ld_u64_agent(const u64* p){
  return __hip_atomic_load(p, __ATOMIC_RELAXED, __HIP_MEMORY_SCOPE_AGENT);
}
__device__ __forceinline__ void st_u64_agent(u64* p, u64 v){
  __hip_atomic_store(p, v, __ATOMIC_RELAXED, __HIP_MEMORY_SCOPE_AGENT);
}

// ---------------- convert f32 -> bf16 ----------------
__global__ __launch_bounds__(256) void k_convert(const float* __restrict__ in, bf16* __restrict__ outp, int n){
  int i = (blockIdx.x*256 + threadIdx.x)*4;
  if (i >= n) return;
  f32x4 v = *(const f32x4*)&in[i];
  alignas(8) bf16 tmp[4] = {__float2bfloat16(v.x), __float2bfloat16(v.y), __float2bfloat16(v.z), __float2bfloat16(v.w)};
  *(uint64_t*)&outp[i] = *(const uint64_t*)tmp;
}

// ---------------- encoder embedding gather -> Xe[t*16+b][e] (bf16) ----------------
__global__ __launch_bounds__(256) void k_embed(const int* __restrict__ enc_in, const float* __restrict__ emb,
                                               bf16* __restrict__ Xe){
  int i = blockIdx.x*256 + threadIdx.x;
  int o = i*4;
  int row = o >> 9, e = o & 511;
  int t = row >> 4, b = row & 15;
  int tok = enc_in[b*512 + t];
  f32x4 v = *(const f32x4*)&emb[(size_t)tok*512 + e];
  alignas(8) bf16 tmp[4] = {__float2bfloat16(v.x), __float2bfloat16(v.y), __float2bfloat16(v.z), __float2bfloat16(v.w)};
  *(uint64_t*)&Xe[o] = *(const uint64_t*)tmp;
}

// ---------------- bf16 MFMA GEMM: C[M][N] = A[M][K] * B[N][K]^T + bias ----------------
template<int OUT_BF16>
__global__ __launch_bounds__(256) void k_gemm(
    const bf16* __restrict__ A, const bf16* __restrict__ Bm,
    const float* __restrict__ bias1, const float* __restrict__ bias2,
    void* __restrict__ Cp, int M, int N, int K)
{
  __shared__ bf16 Al[128*32];
  __shared__ bf16 Bl[128*32];
  const int tid = threadIdx.x;
  const int n0 = blockIdx.x*128, m0 = blockIdx.y*128;
  const int wv = tid >> 6, lane = tid & 63;
  const int wr = (wv >> 1)*64, wc = (wv & 1)*64;
  const int lrow = lane & 15, lk = (lane >> 4)*8;
  const int r1 = tid >> 2, kq = (tid & 3)*8;

  f32x4 acc[4][4];
  #pragma unroll
  for (int i=0;i<4;++i)
    #pragma unroll
    for (int j=0;j<4;++j) { f32x4 z = {0.f,0.f,0.f,0.f}; acc[i][j] = z; }

  const bf16* pa0 = &A[(size_t)(m0 + r1)*K + kq];
  const bf16* pa1 = &A[(size_t)(m0 + 64 + r1)*K + kq];
  const bf16* pb0 = &Bm[(size_t)(n0 + r1)*K + kq];
  const bf16* pb1 = &Bm[(size_t)(n0 + 64 + r1)*K + kq];

  u32x4 a0 = *(const u32x4*)pa0, a1 = *(const u32x4*)pa1;
  u32x4 b0 = *(const u32x4*)pb0, b1 = *(const u32x4*)pb1;

  const int nk = K >> 5;
  for (int kt = 0; kt < nk; ++kt) {
    __syncthreads();
    *(u32x4*)&Al[r1*32 + kq]        = a0;
    *(u32x4*)&Al[(64 + r1)*32 + kq] = a1;
    *(u32x4*)&Bl[r1*32 + kq]        = b0;
    *(u32x4*)&Bl[(64 + r1)*32 + kq] = b1;
    __syncthreads();
    if (kt + 1 < nk) {
      int off = (kt+1)*32;
      a0 = *(const u32x4*)(pa0 + off); a1 = *(const u32x4*)(pa1 + off);
      b0 = *(const u32x4*)(pb0 + off); b1 = *(const u32x4*)(pb1 + off);
    }
    s16x8 af[4], bfr[4];
    #pragma unroll
    for (int mi=0;mi<4;++mi) af[mi]  = *(const s16x8*)&Al[(wr + mi*16 + lrow)*32 + lk];
    #pragma unroll
    for (int ni=0;ni<4;++ni) bfr[ni] = *(const s16x8*)&Bl[(wc + ni*16 + lrow)*32 + lk];
    #pragma unroll
    for (int mi=0;mi<4;++mi)
      #pragma unroll
      for (int ni=0;ni<4;++ni)
        acc[mi][ni] = __builtin_amdgcn_mfma_f32_16x16x32_bf16(af[mi], bfr[ni], acc[mi][ni], 0, 0, 0);
  }
  const int crow = (lane >> 4)*4;
  #pragma unroll
  for (int mi=0;mi<4;++mi) {
    #pragma unroll
    for (int ni=0;ni<4;++ni) {
      int cc = n0 + wc + ni*16 + lrow;
      float badd = (bias1 ? bias1[cc] : 0.f) + (bias2 ? bias2[cc] : 0.f);
      #pragma unroll
      for (int q=0;q<4;++q) {
        int rr = m0 + wr + mi*16 + crow + q;
        float v = acc[mi][ni][q] + badd;
        if (OUT_BF16) ((bf16*)Cp)[(size_t)rr*N + cc] = __float2bfloat16(v);
        else          ((float*)Cp)[(size_t)rr*N + cc] = v;
      }
    }
  }
}

// ---------------- encoder recurrence: 512 sequential steps ----------------
// 128 blocks x 512 thr (8 waves). Block owns 4 j's (16 gate-cols).
// Tagged exchange: h_ex[2][8192] u64 entries {tag | f32 h}, slot = (j>>2)*64 + b*4 + (j&3).
// Producer stores tagged u64 (no ack, no flag). Consumer: 16 slots/thread
// (q*512+tid, q<16 -> all 8192); the data load IS the poll.
// Thread matvec role: ksl = tid&15 (32-float k-slice), col2 = (tid>>4)&7
// (column pair: g = col2>>1, jl0 = (col2&1)*2), bgrp = tid>>7 (4 batches).
__global__ __launch_bounds__(512, 1) void k_encoder(
    const bf16* __restrict__ GXe, const float* __restrict__ w_hh,
    u64* __restrict__ h_ex, float* __restrict__ c_glob,
    float* __restrict__ enc_out)
{
  const int tid = threadIdx.x, bid = blockIdx.x;
  const int ksl  = tid & 15;
  const int col2 = (tid >> 4) & 7;
  const int g = col2 >> 1, jl0 = (col2 & 1)*2;
  const int bgrp = tid >> 7;

  __shared__ float h_lds[16*520];
  __shared__ float gate_lds[16*20];
  __shared__ float h_out_l[64];

  // weights: 2 jl columns x 32 k, bank-rotated k-quad order (matched at use)
  f32x4 wreg[2][8];
  #pragma unroll
  for (int jj = 0; jj < 2; ++jj) {
    const float* wrow = &w_hh[(size_t)(g*512 + bid*4 + jl0 + jj)*512 + ksl*32];
    #pragma unroll
    for (int i = 0; i < 8; ++i) {
      int kk = (i + ksl) & 7;
      wreg[jj][i] = *(const f32x4*)&wrow[kk*4];
    }
  }
  float c_reg = 0.f;                                  // producers tid<64
  const int pb = tid & 15, pjl = tid >> 4;            // producer mapping (wave 0)

  for (int t = 0; t < 512; ++t) {
    // prefetch GXe for finalizer lanes: 2 contiguous bf16 (u32) per batch
    uint32_t gx[4];
    if (ksl == 0) {
      #pragma unroll
      for (int bi = 0; bi < 4; ++bi)
        gx[bi] = *(const uint32_t*)&GXe[(size_t)(t*16 + bgrp*4 + bi)*2048 + g*512 + bid*4 + jl0];
    }
    float acc[4][2];
    #pragma unroll
    for (int bi=0;bi<4;++bi) { acc[bi][0] = 0.f; acc[bi][1] = 0.f; }

    if (t > 0) {
      const u64* hg = h_ex + (t & 1)*8192;
      const uint32_t tag = (uint32_t)t;      // h_t carries tag t
      u64 hv[16];
      #pragma unroll
      for (int q = 0; q < 16; ++q) hv[q] = ld_u64_agent(&hg[q*512 + tid]);
      uint32_t pend = 0xffffu, spins = 0;
      while (pend) {
        #pragma unroll
        for (int q = 0; q < 16; ++q) {
          if (pend & (1u << q)) {
            if ((uint32_t)(hv[q] >> 32) == tag) {
              int u = q*512 + tid;
              int bid2 = u >> 6, rem = u & 63, bb = rem >> 2, jl = rem & 3;
              h_lds[bb*520 + bid2*4 + jl] = __uint_as_float((uint32_t)hv[q]);
              pend &= ~(1u << q);
            } else {
              hv[q] = ld_u64_agent(&hg[q*512 + tid]);
            }
          }
        }
        if (++spins > (1u<<20)) break;   // broken protocol -> visible failure
      }
      __syncthreads();                                 // (B)
      #pragma unroll
      for (int bi = 0; bi < 4; ++bi) {
        const float* hrow = &h_lds[(bgrp*4 + bi)*520 + ksl*32];
        #pragma unroll
        for (int i = 0; i < 8; ++i) {
          int kk = (i + ksl) & 7;
          f32x4 hv4 = *(const f32x4*)&hrow[kk*4];
          #pragma unroll
          for (int jj = 0; jj < 2; ++jj) {
            acc[bi][jj] = __fmaf_rn(hv4.x, wreg[jj][i].x, acc[bi][jj]);
            acc[bi][jj] = __fmaf_rn(hv4.y, wreg[jj][i].y, acc[bi][jj]);
            acc[bi][jj] = __fmaf_rn(hv4.z, wreg[jj][i].z, acc[bi][jj]);
            acc[bi][jj] = __fmaf_rn(hv4.w, wreg[jj][i].w, acc[bi][jj]);
          }
        }
      }
      // in-wave reduce over 16 ksl lanes
      #pragma unroll
      for (int bi = 0; bi < 4; ++bi)
        #pragma unroll
        for (int jj = 0; jj < 2; ++jj) {
          float v = acc[bi][jj];
          v += __shfl_xor(v, 1);
          v += __shfl_xor(v, 2);
          v += __shfl_xor(v, 4);
          v += __shfl_xor(v, 8);
          acc[bi][jj] = v;
        }
    }
    if (ksl == 0) {
      #pragma unroll
      for (int bi = 0; bi < 4; ++bi) {
        #pragma unroll
        for (int jj = 0; jj < 2; ++jj) {
          uint32_t hbits = ((gx[bi] >> (16*jj)) & 0xffffu) << 16;
          float gxf = __uint_as_float(hbits);
          gate_lds[(bgrp*4 + bi)*20 + g*4 + jl0 + jj] = acc[bi][jj] + gxf;
        }
      }
    }
    __syncthreads();                                   // (D)
    if (tid < 64) {
      float gi = gate_lds[pb*20 +      pjl];
      float gf = gate_lds[pb*20 +  4 + pjl];
      float gg = gate_lds[pb*20 +  8 + pjl];
      float go = gate_lds[pb*20 + 12 + pjl];
      float cn = sigf(gf)*c_reg + sigf(gi)*tanh_f(gg);
      float hn = sigf(go)*tanh_f(cn);
      c_reg = cn;
      u64 payload = ((u64)(uint32_t)(t + 1) << 32) | (u64)__float_as_uint(hn);
      st_u64_agent(&h_ex[((t+1) & 1)*8192 + bid*64 + pb*4 + pjl], payload);
      h_out_l[tid] = hn;
    }
    __syncthreads();                                   // (E)
    if (tid >= 64 && tid < 128) {
      int ob = (tid - 64) & 15, ojl = (tid - 64) >> 4;
      enc_out[((size_t)ob*512 + t)*512 + bid*4 + ojl] = h_out_l[tid - 64];
    }
  }
  if (tid < 64) c_glob[pb*512 + bid*4 + pjl] = c_reg;
}

// ---------------- gates for decoder step 0 (hT from tagged h_ex[0], low words) ----------------
__global__ __launch_bounds__(128) void k_gates0(
    const int* __restrict__ dec_in, const float* __restrict__ emb,
    const u64* __restrict__ hT64,   // h_exE[0]: slot (k>>2)*64 + b*4 + (k&3)
    const float* __restrict__ w_ih, const float* __restrict__ w_hh,
    const float* __restrict__ b_ih, const float* __restrict__ b_hh,
    float* __restrict__ g0)
{
  int gt = blockIdx.x*128 + threadIdx.x;
  int b = gt & 15, col = gt >> 4;
  const float* x0 = &emb[(size_t)dec_in[b*128] * 512];
  const float* wi = &w_ih[(size_t)col*512];
  const float* wh = &w_hh[(size_t)col*512];
  float s0=0.f, s1=0.f;
  for (int k4 = 0; k4 < 128; ++k4) {
    const u64* hp = &hT64[k4*64 + b*4];
    float h0 = __uint_as_float((uint32_t)hp[0]);
    float h1 = __uint_as_float((uint32_t)hp[1]);
    float h2 = __uint_as_float((uint32_t)hp[2]);
    float h3 = __uint_as_float((uint32_t)hp[3]);
    f32x4 xv  = *(const f32x4*)&x0[k4*4];
    f32x4 wiv = *(const f32x4*)&wi[k4*4];
    f32x4 whv = *(const f32x4*)&wh[k4*4];
    s0 += xv.x*wiv.x + xv.y*wiv.y + xv.z*wiv.z + xv.w*wiv.w;
    s1 += h0*whv.x + h1*whv.y + h2*whv.z + h3*whv.w;
  }
  g0[b*2048 + col] = s0 + s1 + b_ih[col] + b_hh[col];
}

// ---------------- decoder recurrence: 128 sequential steps (x_t == h_t for t>=1) ----------------
__global__ __launch_bounds__(512, 1) void k_decoder(
    const float* __restrict__ w_ih, const float* __restrict__ w_hh,
    const float* __restrict__ b_ih, const float* __restrict__ b_hh,
    const float* __restrict__ gates0,
    u64* __restrict__ h_ex, const float* __restrict__ c_glob,
    float* __restrict__ dec_h, bf16* __restrict__ dec_out)
{
  const int tid = threadIdx.x, bid = blockIdx.x;
  const int ksl  = tid & 15;
  const int col2 = (tid >> 4) & 7;
  const int g = col2 >> 1, jl0 = (col2 & 1)*2;
  const int bgrp = tid >> 7;

  __shared__ float h_lds[16*520];
  __shared__ float gate_lds[16*20];
  __shared__ float h_out_l[64];

  f32x4 wreg[2][8];
  float bias_j[2];
  #pragma unroll
  for (int jj = 0; jj < 2; ++jj) {
    int colg = g*512 + bid*4 + jl0 + jj;
    bias_j[jj] = b_ih[colg] + b_hh[colg];
    const float* wrowa = &w_ih[(size_t)colg*512 + ksl*32];
    const float* wrowb = &w_hh[(size_t)colg*512 + ksl*32];
    #pragma unroll
    for (int i = 0; i < 8; ++i) {
      int kk = (i + ksl) & 7;
      f32x4 wa = *(const f32x4*)&wrowa[kk*4];
      f32x4 wb = *(const f32x4*)&wrowb[kk*4];
      wreg[jj][i] = wa + wb;
    }
  }
  const int pb = tid & 15, pjl = tid >> 4;
  float c_reg = 0.f;
  if (tid < 64) c_reg = c_glob[pb*512 + bid*4 + pjl];

  for (int t = 0; t < 128; ++t) {
    float acc[4][2];
    #pragma unroll
    for (int bi=0;bi<4;++bi) { acc[bi][0] = 0.f; acc[bi][1] = 0.f; }

    if (t > 0) {
      const u64* hg = h_ex + (t & 1)*8192;
      const uint32_t tag = (uint32_t)t;
      u64 hv[16];
      #pragma unroll
      for (int q = 0; q < 16; ++q) hv[q] = ld_u64_agent(&hg[q*512 + tid]);
      uint32_t pend = 0xffffu, spins = 0;
      while (pend) {
        #pragma unroll
        for (int q = 0; q < 16; ++q) {
          if (pend & (1u << q)) {
            if ((uint32_t)(hv[q] >> 32) == tag) {
              int u = q*512 + tid;
              int bid2 = u >> 6, rem = u & 63, bb = rem >> 2, jl = rem & 3;
              h_lds[bb*520 + bid2*4 + jl] = __uint_as_float((uint32_t)hv[q]);
              pend &= ~(1u << q);
            } else {
              hv[q] = ld_u64_agent(&hg[q*512 + tid]);
            }
          }
        }
        if (++spins > (1u<<20)) break;
      }
      __syncthreads();                                 // (B)
      #pragma unroll
      for (int bi = 0; bi < 4; ++bi) {
        const float* hrow = &h_lds[(bgrp*4 + bi)*520 + ksl*32];
        #pragma unroll
        for (int i = 0; i < 8; ++i) {
          int kk = (i + ksl) & 7;
          f32x4 hv4 = *(const f32x4*)&hrow[kk*4];
          #pragma unroll
          for (int jj = 0; jj < 2; ++jj) {
            acc[bi][jj] = __fmaf_rn(hv4.x, wreg[jj][i].x, acc[bi][jj]);
            acc[bi][jj] = __fmaf_rn(hv4.y, wreg[jj][i].y, acc[bi][jj]);
            acc[bi][jj] = __fmaf_rn(hv4.z, wreg[jj][i].z, acc[bi][jj]);
            acc[bi][jj] = __fmaf_rn(hv4.w, wreg[jj][i].w, acc[bi][jj]);
          }
        }
      }
      #pragma unroll
      for (int bi = 0; bi < 4; ++bi)
        #pragma unroll
        for (int jj = 0; jj < 2; ++jj) {
          float v = acc[bi][jj];
          v += __shfl_xor(v, 1);
          v += __shfl_xor(v, 2);
          v += __shfl_xor(v, 4);
          v += __shfl_xor(v, 8);
          acc[bi][jj] = v;
        }
    }
    if (ksl == 0) {
      if (t == 0) {
        #pragma unroll
        for (int bi = 0; bi < 4; ++bi) {
          f32x2 gv = *(const f32x2*)&gates0[(size_t)(bgrp*4 + bi)*2048 + g*512 + bid*4 + jl0];
          gate_lds[(bgrp*4 + bi)*20 + g*4 + jl0 + 0] = gv.x;
          gate_lds[(bgrp*4 + bi)*20 + g*4 + jl0 + 1] = gv.y;
        }
      } else {
        #pragma unroll
        for (int bi = 0; bi < 4; ++bi)
          #pragma unroll
          for (int jj = 0; jj < 2; ++jj)
            gate_lds[(bgrp*4 + bi)*20 + g*4 + jl0 + jj] = acc[bi][jj] + bias_j[jj];
      }
    }
    __syncthreads();                                   // (D)
    if (tid < 64) {
      float gi = gate_lds[pb*20 +      pjl];
      float gf = gate_lds[pb*20 +  4 + pjl];
      float gg = gate_lds[pb*20 +  8 + pjl];
      float go = gate_lds[pb*20 + 12 + pjl];
      float cn = sigf(gf)*c_reg + sigf(gi)*tanh_f(gg);
      float hn = sigf(go)*tanh_f(cn);
      c_reg = cn;
      u64 payload = ((u64)(uint32_t)(t + 1) << 32) | (u64)__float_as_uint(hn);
      st_u64_agent(&h_ex[((t+1) & 1)*8192 + bid*64 + pb*4 + pjl], payload);
      h_out_l[tid] = hn;
    }
    __syncthreads();                                   // (E)
    if (tid >= 64 && tid < 128) {
      int ob = (tid - 64) & 15, ojl = (tid - 64) >> 4;
      float hn = h_out_l[tid - 64];
      int jgl = bid*4 + ojl;
      dec_h[((size_t)t*16 + ob)*512 + jgl] = hn;
      dec_out[((size_t)(ob*128 + t))*1024 + jgl] = __float2bfloat16(hn);
    }
  }
}

// ---------------- batched attention over all (t,b) ----------------
__global__ __launch_bounds__(256) void k_attn(
    const float* __restrict__ dec_h, const float* __restrict__ enc_out,
    bf16* __restrict__ dOut)
{
  const int tid = threadIdx.x, bid = blockIdx.x;
  const int b = bid >> 3, t0 = (bid & 7)*16;
  __shared__ float h16[16*512];
  __shared__ float sc[16*512];
  #pragma unroll
  for (int q = 0; q < 8; ++q) {
    int fi = q*256 + tid;
    int tt = fi >> 7, e4 = (fi & 127)*4;
    *(f32x4*)&h16[tt*512 + e4] = *(const f32x4*)&dec_h[((size_t)(t0 + tt)*16 + b)*512 + e4];
  }
  __syncthreads();
  const float* encb = &enc_out[(size_t)b*512*512];
  for (int si = 0; si < 2; ++si) {
    int s = si*256 + tid;
    float a[16];
    #pragma unroll
    for (int tt=0;tt<16;++tt) a[tt]=0.f;
    for (int e4 = 0; e4 < 512; e4 += 4) {
      f32x4 ev = *(const f32x4*)&encb[(size_t)s*512 + e4];
      #pragma unroll
      for (int tt = 0; tt < 16; ++tt) {
        f32x4 hv = *(const f32x4*)&h16[tt*512 + e4];
        a[tt] += ev.x*hv.x + ev.y*hv.y + ev.z*hv.z + ev.w*hv.w;
      }
    }
    #pragma unroll
    for (int tt=0;tt<16;++tt) sc[tt*512 + s] = a[tt];
  }
  __syncthreads();
  {
    int wv = tid >> 6, lane = tid & 63;
    #pragma unroll
    for (int u = 0; u < 4; ++u) {
      int tt = wv*4 + u;
      float x[8];
      float m = -1e30f;
      #pragma unroll
      for (int i=0;i<8;++i){ x[i] = sc[tt*512 + i*64 + lane]; m = fmaxf(m, x[i]); }
      #pragma unroll
      for (int off=1; off<64; off<<=1) m = fmaxf(m, __shfl_xor(m, off));
      float sum = 0.f;
      #pragma unroll
      for (int i=0;i<8;++i){ x[i] = __expf(x[i]-m); sum += x[i]; }
      #pragma unroll
      for (int off=1; off<64; off<<=1) sum += __shfl_xor(sum, off);
      float inv = 1.f/sum;
      #pragma unroll
      for (int i=0;i<8;++i) sc[tt*512 + i*64 + lane] = x[i]*inv;
    }
  }
  __syncthreads();
  {
    int e0 = tid*2;
    float cx[16], cy[16];
    #pragma unroll
    for (int tt=0;tt<16;++tt){ cx[tt]=0.f; cy[tt]=0.f; }
    for (int s = 0; s < 512; ++s) {
      f32x2 ev = *(const f32x2*)&encb[(size_t)s*512 + e0];
      #pragma unroll
      for (int tt = 0; tt < 16; ++tt) {
        float aw = sc[tt*512 + s];
        cx[tt] += aw*ev.x; cy[tt] += aw*ev.y;
      }
    }
    #pragma unroll
    for (int tt = 0; tt < 16; ++tt) {
      size_t rowo = ((size_t)(b*128 + t0 + tt))*1024 + 512 + e0;
      alignas(4) bf16 tmp[2] = {__float2bfloat16(cx[tt]), __float2bfloat16(cy[tt])};
      *(uint32_t*)&dOut[rowo] = *(const uint32_t*)tmp;
    }
  }
}

// ---------------- host ----------------
extern "C" void kernel_launch(void* const* d_in, const int* in_sizes, int n_in,
                              void* d_out, int out_size, void* d_ws, size_t ws_size,
                              hipStream_t stream)
{
  const int*   enc_in = (const int*)d_in[0];
  const int*   dec_in = (const int*)d_in[1];
  const float* emb    = (const float*)d_in[2];
  const float* w_ih_e = (const float*)d_in[3];
  const float* w_hh_e = (const float*)d_in[4];
  const float* b_ih_e = (const float*)d_in[5];
  const float* b_hh_e = (const float*)d_in[6];
  const float* w_ih_d = (const float*)d_in[7];
  const float* w_hh_d = (const float*)d_in[8];
  const float* b_ih_d = (const float*)d_in[9];
  const float* b_hh_d = (const float*)d_in[10];
  const float* w_proj = (const float*)d_in[11];
  const float* b_proj = (const float*)d_in[12];
  float* out = (float*)d_out;

  char* ws = (char*)d_ws;
  size_t off = 0;
  auto alloc = [&](size_t bytes)->void* { void* p = ws + off; off += (bytes + 255) & ~(size_t)255; return p; };
  bf16*  Wp      = (bf16*)alloc(32000ull*1024*2);
  bf16*  Xe      = (bf16*)alloc(8192ull*512*2);
  bf16*  Wie     = (bf16*)alloc(2048ull*512*2);
  bf16*  GXe     = (bf16*)alloc(8192ull*2048*2);
  float* enc_out = (float*)alloc(16ull*512*512*4);
  float* dec_h   = (float*)alloc(128ull*16*512*4);
  bf16*  dOutB   = (bf16*)alloc(2048ull*1024*2);
  u64*   h_exE   = (u64*)alloc(2*8192ull*8);        // [2][8192] tagged u64
  u64*   h_exD   = (u64*)alloc(2*8192ull*8);
  float* c_g     = (float*)alloc(16*512*4);
  float* g0      = (float*)alloc(16*2048*4);
  if (off > ws_size) return;  // workspace too small -> fail validation loudly

  // zero tags (prevents stale-tag acceptance across graph replays)
  (void)hipMemsetAsync(h_exE, 0, 2*8192ull*8, stream);
  (void)hipMemsetAsync(h_exD, 0, 2*8192ull*8, stream);

  k_convert<<<32000, 256, 0, stream>>>(w_proj, Wp, 32768000);
  k_convert<<<1024, 256, 0, stream>>>(w_ih_e, Wie, 1048576);
  k_embed<<<4096, 256, 0, stream>>>(enc_in, emb, Xe);
  // encoder input gates for all timesteps: GXe = Xe @ w_ih_e^T + (b_ih_e + b_hh_e)
  k_gemm<1><<<dim3(16, 64), 256, 0, stream>>>(Xe, Wie, b_ih_e, b_hh_e, GXe, 8192, 2048, 512);
  k_encoder<<<NBLK, 512, 0, stream>>>(GXe, w_hh_e, h_exE, c_g, enc_out);
  // final encoder h lands in h_exE[0] (t=511 writes buf (512&1)=0), tagged layout
  k_gates0<<<256, 128, 0, stream>>>(dec_in, emb, h_exE, w_ih_d, w_hh_d, b_ih_d, b_hh_d, g0);
  k_decoder<<<NBLK, 512, 0, stream>>>(w_ih_d, w_hh_d, b_ih_d, b_hh_d, g0, h_exD, c_g, dec_h, dOutB);
  k_attn<<<128, 256, 0, stream>>>(dec_h, enc_out, dOutB);
  // logits = dec_out @ w_proj^T + b_proj
  k_gemm<0><<<dim3(250, 16), 256, 0, stream>>>(dOutB, Wp, b_proj, nullptr, out, 2048, 32000, 1024);
}

// Round 8
// 1723.268 us; speedup vs baseline: 3.0538x; 2.8441x over previous
//
#include <hip/hip_runtime.h>
#include <hip/hip_bf16.h>
#include <stdint.h>

typedef __attribute__((ext_vector_type(4))) float f32x4;
typedef __attribute__((ext_vector_type(2))) float f32x2;
typedef __attribute__((ext_vector_type(8))) short s16x8;
typedef __attribute__((ext_vector_type(4))) uint32_t u32x4;
typedef __hip_bfloat16 bf16;
typedef unsigned long long u64;

__device__ __forceinline__ float sigf(float x){ return 1.f/(1.f+__expf(-x)); }
__device__ __forceinline__ float tanh_f(float x){ float e=__expf(2.f*x); return (e-1.f)/(e+1.f); }

__device__ __forceinline__ u64 ld_u64_agent(const u64* p){
  return __hip_atomic_load(p, __ATOMIC_RELAXED, __HIP_MEMORY_SCOPE_AGENT);
}
__device__ __forceinline__ void st_u64_agent(u64* p, u64 v){
  __hip_atomic_store(p, v, __ATOMIC_RELAXED, __HIP_MEMORY_SCOPE_AGENT);
}

// ---------------- convert f32 -> bf16 ----------------
__global__ __launch_bounds__(256) void k_convert(const float* __restrict__ in, bf16* __restrict__ outp, int n){
  int i = (blockIdx.x*256 + threadIdx.x)*4;
  if (i >= n) return;
  f32x4 v = *(const f32x4*)&in[i];
  alignas(8) bf16 tmp[4] = {__float2bfloat16(v.x), __float2bfloat16(v.y), __float2bfloat16(v.z), __float2bfloat16(v.w)};
  *(uint64_t*)&outp[i] = *(const uint64_t*)tmp;
}

// ---------------- encoder embedding gather -> Xe[t*16+b][e] (bf16) ----------------
__global__ __launch_bounds__(256) void k_embed(const int* __restrict__ enc_in, const float* __restrict__ emb,
                                               bf16* __restrict__ Xe){
  int i = blockIdx.x*256 + threadIdx.x;
  int o = i*4;
  int row = o >> 9, e = o & 511;
  int t = row >> 4, b = row & 15;
  int tok = enc_in[b*512 + t];
  f32x4 v = *(const f32x4*)&emb[(size_t)tok*512 + e];
  alignas(8) bf16 tmp[4] = {__float2bfloat16(v.x), __float2bfloat16(v.y), __float2bfloat16(v.z), __float2bfloat16(v.w)};
  *(uint64_t*)&Xe[o] = *(const uint64_t*)tmp;
}

// ---------------- bf16 MFMA GEMM: C[M][N] = A[M][K] * B[N][K]^T + bias ----------------
template<int OUT_BF16>
__global__ __launch_bounds__(256) void k_gemm(
    const bf16* __restrict__ A, const bf16* __restrict__ Bm,
    const float* __restrict__ bias1, const float* __restrict__ bias2,
    void* __restrict__ Cp, int M, int N, int K)
{
  __shared__ bf16 Al[128*32];
  __shared__ bf16 Bl[128*32];
  const int tid = threadIdx.x;
  const int n0 = blockIdx.x*128, m0 = blockIdx.y*128;
  const int wv = tid >> 6, lane = tid & 63;
  const int wr = (wv >> 1)*64, wc = (wv & 1)*64;
  const int lrow = lane & 15, lk = (lane >> 4)*8;
  const int r1 = tid >> 2, kq = (tid & 3)*8;

  f32x4 acc[4][4];
  #pragma unroll
  for (int i=0;i<4;++i)
    #pragma unroll
    for (int j=0;j<4;++j) { f32x4 z = {0.f,0.f,0.f,0.f}; acc[i][j] = z; }

  const bf16* pa0 = &A[(size_t)(m0 + r1)*K + kq];
  const bf16* pa1 = &A[(size_t)(m0 + 64 + r1)*K + kq];
  const bf16* pb0 = &Bm[(size_t)(n0 + r1)*K + kq];
  const bf16* pb1 = &Bm[(size_t)(n0 + 64 + r1)*K + kq];

  u32x4 a0 = *(const u32x4*)pa0, a1 = *(const u32x4*)pa1;
  u32x4 b0 = *(const u32x4*)pb0, b1 = *(const u32x4*)pb1;

  const int nk = K >> 5;
  for (int kt = 0; kt < nk; ++kt) {
    __syncthreads();
    *(u32x4*)&Al[r1*32 + kq]        = a0;
    *(u32x4*)&Al[(64 + r1)*32 + kq] = a1;
    *(u32x4*)&Bl[r1*32 + kq]        = b0;
    *(u32x4*)&Bl[(64 + r1)*32 + kq] = b1;
    __syncthreads();
    if (kt + 1 < nk) {
      int off = (kt+1)*32;
      a0 = *(const u32x4*)(pa0 + off); a1 = *(const u32x4*)(pa1 + off);
      b0 = *(const u32x4*)(pb0 + off); b1 = *(const u32x4*)(pb1 + off);
    }
    s16x8 af[4], bfr[4];
    #pragma unroll
    for (int mi=0;mi<4;++mi) af[mi]  = *(const s16x8*)&Al[(wr + mi*16 + lrow)*32 + lk];
    #pragma unroll
    for (int ni=0;ni<4;++ni) bfr[ni] = *(const s16x8*)&Bl[(wc + ni*16 + lrow)*32 + lk];
    #pragma unroll
    for (int mi=0;mi<4;++mi)
      #pragma unroll
      for (int ni=0;ni<4;++ni)
        acc[mi][ni] = __builtin_amdgcn_mfma_f32_16x16x32_bf16(af[mi], bfr[ni], acc[mi][ni], 0, 0, 0);
  }
  const int crow = (lane >> 4)*4;
  #pragma unroll
  for (int mi=0;mi<4;++mi) {
    #pragma unroll
    for (int ni=0;ni<4;++ni) {
      int cc = n0 + wc + ni*16 + lrow;
      float badd = (bias1 ? bias1[cc] : 0.f) + (bias2 ? bias2[cc] : 0.f);
      #pragma unroll
      for (int q=0;q<4;++q) {
        int rr = m0 + wr + mi*16 + crow + q;
        float v = acc[mi][ni][q] + badd;
        if (OUT_BF16) ((bf16*)Cp)[(size_t)rr*N + cc] = __float2bfloat16(v);
        else          ((float*)Cp)[(size_t)rr*N + cc] = v;
      }
    }
  }
}

// ============ per-batch recurrence groups ============
// 256 blocks = 16 batch-groups x 16 blocks. Block (b, r) owns j in [r*32, r*32+32)
// i.e. in-block gate-cols ic in [0,128): global col = (ic>>5)*512 + r*32 + (ic&31).
// Thread (ksl=tid&15, c=tid>>4) holds 4 cols' weights (wreg[4][8] f32x4 = 128 VGPR).
// Exchange per group: hex[b][2][512] tagged u64 {tag=t | f32 h}. One slot/thread.
// Publish (32 producer threads) is after a block barrier that follows all reads,
// so double-buffer overwrite safety holds by induction (R6 protocol).

// ---------------- encoder recurrence ----------------
__global__ __launch_bounds__(512, 1) void k_enc_r(
    const bf16* __restrict__ GXe, const float* __restrict__ w_hh,
    u64* __restrict__ hex, float* __restrict__ cT, float* __restrict__ hT,
    float* __restrict__ enc_out)
{
  const int tid = threadIdx.x, bid = blockIdx.x;
  const int b = bid >> 4, r = bid & 15;
  const int ksl = tid & 15, c = tid >> 4;

  __shared__ float h_lds[512];
  __shared__ float gate_lds[128];

  f32x4 wreg[4][8];
  #pragma unroll
  for (int cc = 0; cc < 4; ++cc) {
    int ic = c*4 + cc;
    int gc = (ic >> 5)*512 + r*32 + (ic & 31);
    const float* wrow = &w_hh[(size_t)gc*512 + ksl*32];
    #pragma unroll
    for (int i = 0; i < 8; ++i) wreg[cc][i] = *(const f32x4*)&wrow[((i + ksl) & 7)*4];
  }
  const int gc0 = ((c*4) >> 5)*512 + r*32 + ((c*4) & 31);
  u64* hb = hex + (size_t)b*1024;
  float c_reg = 0.f;
  const int jg = r*32 + tid;   // producer's j (tid<32)

  for (int t = 0; t < 512; ++t) {
    uint64_t gx = 0;
    if (ksl == 0) gx = *(const uint64_t*)&GXe[(size_t)(t*16 + b)*2048 + gc0];
    float a0=0.f, a1=0.f, a2=0.f, a3=0.f;
    if (t > 0) {
      const uint32_t tg = (uint32_t)t;
      u64* slot = &hb[(t & 1)*512 + tid];
      u64 v = ld_u64_agent(slot);
      uint32_t spins = 0;
      while ((uint32_t)(v >> 32) != tg) {
        v = ld_u64_agent(slot);
        if (++spins > (1u<<18)) break;      // broken protocol -> bounded, visible failure
      }
      h_lds[tid] = __uint_as_float((uint32_t)v);
      __syncthreads();                       // (B)
      const float* hrow = &h_lds[ksl*32];
      #pragma unroll
      for (int i = 0; i < 8; ++i) {
        f32x4 hv = *(const f32x4*)&hrow[((i + ksl) & 7)*4];
        a0 = __fmaf_rn(hv.x, wreg[0][i].x, a0); a0 = __fmaf_rn(hv.y, wreg[0][i].y, a0);
        a0 = __fmaf_rn(hv.z, wreg[0][i].z, a0); a0 = __fmaf_rn(hv.w, wreg[0][i].w, a0);
        a1 = __fmaf_rn(hv.x, wreg[1][i].x, a1); a1 = __fmaf_rn(hv.y, wreg[1][i].y, a1);
        a1 = __fmaf_rn(hv.z, wreg[1][i].z, a1); a1 = __fmaf_rn(hv.w, wreg[1][i].w, a1);
        a2 = __fmaf_rn(hv.x, wreg[2][i].x, a2); a2 = __fmaf_rn(hv.y, wreg[2][i].y, a2);
        a2 = __fmaf_rn(hv.z, wreg[2][i].z, a2); a2 = __fmaf_rn(hv.w, wreg[2][i].w, a2);
        a3 = __fmaf_rn(hv.x, wreg[3][i].x, a3); a3 = __fmaf_rn(hv.y, wreg[3][i].y, a3);
        a3 = __fmaf_rn(hv.z, wreg[3][i].z, a3); a3 = __fmaf_rn(hv.w, wreg[3][i].w, a3);
      }
      #pragma unroll
      for (int s = 1; s < 16; s <<= 1) {
        a0 += __shfl_xor(a0, s); a1 += __shfl_xor(a1, s);
        a2 += __shfl_xor(a2, s); a3 += __shfl_xor(a3, s);
      }
    }
    if (ksl == 0) {
      gate_lds[c*4 + 0] = a0 + __uint_as_float((uint32_t)(gx & 0xffffu) << 16);
      gate_lds[c*4 + 1] = a1 + __uint_as_float((uint32_t)((gx >> 16) & 0xffffu) << 16);
      gate_lds[c*4 + 2] = a2 + __uint_as_float((uint32_t)((gx >> 32) & 0xffffu) << 16);
      gate_lds[c*4 + 3] = a3 + __uint_as_float((uint32_t)((gx >> 48) & 0xffffu) << 16);
    }
    __syncthreads();                          // (D)
    if (tid < 32) {
      float gi = gate_lds[tid];
      float gf = gate_lds[32 + tid];
      float gg = gate_lds[64 + tid];
      float go = gate_lds[96 + tid];
      float cn = sigf(gf)*c_reg + sigf(gi)*tanh_f(gg);
      float hn = sigf(go)*tanh_f(cn);
      c_reg = cn;
      st_u64_agent(&hb[((t+1) & 1)*512 + jg],
                   ((u64)(uint32_t)(t + 1) << 32) | (u64)__float_as_uint(hn));
      enc_out[((size_t)b*512 + t)*512 + jg] = hn;
      if (t == 511) { hT[b*512 + jg] = hn; cT[b*512 + jg] = cn; }
    }
  }
}

// ---------------- gates for decoder step 0 ----------------
__global__ __launch_bounds__(128) void k_gates0(
    const int* __restrict__ dec_in, const float* __restrict__ emb,
    const float* __restrict__ hT,
    const float* __restrict__ w_ih, const float* __restrict__ w_hh,
    const float* __restrict__ b_ih, const float* __restrict__ b_hh,
    float* __restrict__ g0)
{
  int gt = blockIdx.x*128 + threadIdx.x;
  int b = gt & 15, col = gt >> 4;
  const float* x0 = &emb[(size_t)dec_in[b*128] * 512];
  const float* hp = &hT[b*512];
  const float* wi = &w_ih[(size_t)col*512];
  const float* wh = &w_hh[(size_t)col*512];
  float s0=0.f, s1=0.f;
  for (int k = 0; k < 512; k += 4) {
    f32x4 xv = *(const f32x4*)&x0[k]; f32x4 wv = *(const f32x4*)&wi[k];
    f32x4 hv = *(const f32x4*)&hp[k]; f32x4 w2 = *(const f32x4*)&wh[k];
    s0 += xv.x*wv.x + xv.y*wv.y + xv.z*wv.z + xv.w*wv.w;
    s1 += hv.x*w2.x + hv.y*w2.y + hv.z*w2.z + hv.w*w2.w;
  }
  g0[b*2048 + col] = s0 + s1 + b_ih[col] + b_hh[col];
}

// ---------------- decoder recurrence (x_t == h_t for t>=1) ----------------
__global__ __launch_bounds__(512, 1) void k_dec_r(
    const float* __restrict__ w_ih, const float* __restrict__ w_hh,
    const float* __restrict__ b_ih, const float* __restrict__ b_hh,
    const float* __restrict__ gates0,
    u64* __restrict__ hex, const float* __restrict__ cT,
    float* __restrict__ dec_h, bf16* __restrict__ dec_out)
{
  const int tid = threadIdx.x, bid = blockIdx.x;
  const int b = bid >> 4, r = bid & 15;
  const int ksl = tid & 15, c = tid >> 4;

  __shared__ float h_lds[512];
  __shared__ float gate_lds[128];

  f32x4 wreg[4][8];
  float bias_c[4];
  #pragma unroll
  for (int cc = 0; cc < 4; ++cc) {
    int ic = c*4 + cc;
    int gc = (ic >> 5)*512 + r*32 + (ic & 31);
    bias_c[cc] = b_ih[gc] + b_hh[gc];
    const float* wra = &w_ih[(size_t)gc*512 + ksl*32];
    const float* wrb = &w_hh[(size_t)gc*512 + ksl*32];
    #pragma unroll
    for (int i = 0; i < 8; ++i) {
      int o = ((i + ksl) & 7)*4;
      f32x4 wa = *(const f32x4*)&wra[o];
      f32x4 wb = *(const f32x4*)&wrb[o];
      wreg[cc][i] = wa + wb;
    }
  }
  const int gc0 = ((c*4) >> 5)*512 + r*32 + ((c*4) & 31);
  u64* hb = hex + (size_t)b*1024;
  const int jg = r*32 + tid;
  float c_reg = 0.f;
  if (tid < 32) c_reg = cT[b*512 + jg];

  for (int t = 0; t < 128; ++t) {
    float a0=0.f, a1=0.f, a2=0.f, a3=0.f;
    if (t > 0) {
      const uint32_t tg = (uint32_t)t;
      u64* slot = &hb[(t & 1)*512 + tid];
      u64 v = ld_u64_agent(slot);
      uint32_t spins = 0;
      while ((uint32_t)(v >> 32) != tg) {
        v = ld_u64_agent(slot);
        if (++spins > (1u<<18)) break;
      }
      h_lds[tid] = __uint_as_float((uint32_t)v);
      __syncthreads();                       // (B)
      const float* hrow = &h_lds[ksl*32];
      #pragma unroll
      for (int i = 0; i < 8; ++i) {
        f32x4 hv = *(const f32x4*)&hrow[((i + ksl) & 7)*4];
        a0 = __fmaf_rn(hv.x, wreg[0][i].x, a0); a0 = __fmaf_rn(hv.y, wreg[0][i].y, a0);
        a0 = __fmaf_rn(hv.z, wreg[0][i].z, a0); a0 = __fmaf_rn(hv.w, wreg[0][i].w, a0);
        a1 = __fmaf_rn(hv.x, wreg[1][i].x, a1); a1 = __fmaf_rn(hv.y, wreg[1][i].y, a1);
        a1 = __fmaf_rn(hv.z, wreg[1][i].z, a1); a1 = __fmaf_rn(hv.w, wreg[1][i].w, a1);
        a2 = __fmaf_rn(hv.x, wreg[2][i].x, a2); a2 = __fmaf_rn(hv.y, wreg[2][i].y, a2);
        a2 = __fmaf_rn(hv.z, wreg[2][i].z, a2); a2 = __fmaf_rn(hv.w, wreg[2][i].w, a2);
        a3 = __fmaf_rn(hv.x, wreg[3][i].x, a3); a3 = __fmaf_rn(hv.y, wreg[3][i].y, a3);
        a3 = __fmaf_rn(hv.z, wreg[3][i].z, a3); a3 = __fmaf_rn(hv.w, wreg[3][i].w, a3);
      }
      #pragma unroll
      for (int s = 1; s < 16; s <<= 1) {
        a0 += __shfl_xor(a0, s); a1 += __shfl_xor(a1, s);
        a2 += __shfl_xor(a2, s); a3 += __shfl_xor(a3, s);
      }
    }
    if (ksl == 0) {
      if (t == 0) {
        f32x4 gv = *(const f32x4*)&gates0[(size_t)b*2048 + gc0];
        gate_lds[c*4 + 0] = gv.x; gate_lds[c*4 + 1] = gv.y;
        gate_lds[c*4 + 2] = gv.z; gate_lds[c*4 + 3] = gv.w;
      } else {
        gate_lds[c*4 + 0] = a0 + bias_c[0];
        gate_lds[c*4 + 1] = a1 + bias_c[1];
        gate_lds[c*4 + 2] = a2 + bias_c[2];
        gate_lds[c*4 + 3] = a3 + bias_c[3];
      }
    }
    __syncthreads();                          // (D)
    if (tid < 32) {
      float gi = gate_lds[tid];
      float gf = gate_lds[32 + tid];
      float gg = gate_lds[64 + tid];
      float go = gate_lds[96 + tid];
      float cn = sigf(gf)*c_reg + sigf(gi)*tanh_f(gg);
      float hn = sigf(go)*tanh_f(cn);
      c_reg = cn;
      st_u64_agent(&hb[((t+1) & 1)*512 + jg],
                   ((u64)(uint32_t)(t + 1) << 32) | (u64)__float_as_uint(hn));
      dec_h[((size_t)t*16 + b)*512 + jg] = hn;
      dec_out[((size_t)(b*128 + t))*1024 + jg] = __float2bfloat16(hn);
    }
  }
}

// ---------------- batched attention over all (t,b) ----------------
__global__ __launch_bounds__(256) void k_attn(
    const float* __restrict__ dec_h, const float* __restrict__ enc_out,
    bf16* __restrict__ dOut)
{
  const int tid = threadIdx.x, bid = blockIdx.x;
  const int b = bid >> 3, t0 = (bid & 7)*16;
  __shared__ float h16[16*512];
  __shared__ float sc[16*512];
  #pragma unroll
  for (int q = 0; q < 8; ++q) {
    int fi = q*256 + tid;
    int tt = fi >> 7, e4 = (fi & 127)*4;
    *(f32x4*)&h16[tt*512 + e4] = *(const f32x4*)&dec_h[((size_t)(t0 + tt)*16 + b)*512 + e4];
  }
  __syncthreads();
  const float* encb = &enc_out[(size_t)b*512*512];
  for (int si = 0; si < 2; ++si) {
    int s = si*256 + tid;
    float a[16];
    #pragma unroll
    for (int tt=0;tt<16;++tt) a[tt]=0.f;
    for (int e4 = 0; e4 < 512; e4 += 4) {
      f32x4 ev = *(const f32x4*)&encb[(size_t)s*512 + e4];
      #pragma unroll
      for (int tt = 0; tt < 16; ++tt) {
        f32x4 hv = *(const f32x4*)&h16[tt*512 + e4];
        a[tt] += ev.x*hv.x + ev.y*hv.y + ev.z*hv.z + ev.w*hv.w;
      }
    }
    #pragma unroll
    for (int tt=0;tt<16;++tt) sc[tt*512 + s] = a[tt];
  }
  __syncthreads();
  {
    int wv = tid >> 6, lane = tid & 63;
    #pragma unroll
    for (int u = 0; u < 4; ++u) {
      int tt = wv*4 + u;
      float x[8];
      float m = -1e30f;
      #pragma unroll
      for (int i=0;i<8;++i){ x[i] = sc[tt*512 + i*64 + lane]; m = fmaxf(m, x[i]); }
      #pragma unroll
      for (int off=1; off<64; off<<=1) m = fmaxf(m, __shfl_xor(m, off));
      float sum = 0.f;
      #pragma unroll
      for (int i=0;i<8;++i){ x[i] = __expf(x[i]-m); sum += x[i]; }
      #pragma unroll
      for (int off=1; off<64; off<<=1) sum += __shfl_xor(sum, off);
      float inv = 1.f/sum;
      #pragma unroll
      for (int i=0;i<8;++i) sc[tt*512 + i*64 + lane] = x[i]*inv;
    }
  }
  __syncthreads();
  {
    int e0 = tid*2;
    float cx[16], cy[16];
    #pragma unroll
    for (int tt=0;tt<16;++tt){ cx[tt]=0.f; cy[tt]=0.f; }
    for (int s = 0; s < 512; ++s) {
      f32x2 ev = *(const f32x2*)&encb[(size_t)s*512 + e0];
      #pragma unroll
      for (int tt = 0; tt < 16; ++tt) {
        float aw = sc[tt*512 + s];
        cx[tt] += aw*ev.x; cy[tt] += aw*ev.y;
      }
    }
    #pragma unroll
    for (int tt = 0; tt < 16; ++tt) {
      size_t rowo = ((size_t)(b*128 + t0 + tt))*1024 + 512 + e0;
      alignas(4) bf16 tmp[2] = {__float2bfloat16(cx[tt]), __float2bfloat16(cy[tt])};
      *(uint32_t*)&dOut[rowo] = *(const uint32_t*)tmp;
    }
  }
}

// ---------------- host ----------------
extern "C" void kernel_launch(void* const* d_in, const int* in_sizes, int n_in,
                              void* d_out, int out_size, void* d_ws, size_t ws_size,
                              hipStream_t stream)
{
  const int*   enc_in = (const int*)d_in[0];
  const int*   dec_in = (const int*)d_in[1];
  const float* emb    = (const float*)d_in[2];
  const float* w_ih_e = (const float*)d_in[3];
  const float* w_hh_e = (const float*)d_in[4];
  const float* b_ih_e = (const float*)d_in[5];
  const float* b_hh_e = (const float*)d_in[6];
  const float* w_ih_d = (const float*)d_in[7];
  const float* w_hh_d = (const float*)d_in[8];
  const float* b_ih_d = (const float*)d_in[9];
  const float* b_hh_d = (const float*)d_in[10];
  const float* w_proj = (const float*)d_in[11];
  const float* b_proj = (const float*)d_in[12];
  float* out = (float*)d_out;

  char* ws = (char*)d_ws;
  size_t off = 0;
  auto alloc = [&](size_t bytes)->void* { void* p = ws + off; off += (bytes + 255) & ~(size_t)255; return p; };
  bf16*  Wp      = (bf16*)alloc(32000ull*1024*2);
  bf16*  Xe      = (bf16*)alloc(8192ull*512*2);
  bf16*  Wie     = (bf16*)alloc(2048ull*512*2);
  bf16*  GXe     = (bf16*)alloc(8192ull*2048*2);
  float* enc_out = (float*)alloc(16ull*512*512*4);
  float* dec_h   = (float*)alloc(128ull*16*512*4);
  bf16*  dOutB   = (bf16*)alloc(2048ull*1024*2);
  u64*   hexE    = (u64*)alloc(16ull*1024*8);    // [16 groups][2][512] tagged u64
  u64*   hexD    = (u64*)alloc(16ull*1024*8);
  float* cT      = (float*)alloc(16*512*4);
  float* hT      = (float*)alloc(16*512*4);
  float* g0      = (float*)alloc(16*2048*4);
  if (off > ws_size) return;  // workspace too small -> fail validation loudly

  // zero tags in both exchange arenas (contiguous, 256-aligned sizes) each call
  (void)hipMemsetAsync(hexE, 0, 16ull*1024*8*2, stream);

  k_convert<<<32000, 256, 0, stream>>>(w_proj, Wp, 32768000);
  k_convert<<<1024, 256, 0, stream>>>(w_ih_e, Wie, 1048576);
  k_embed<<<4096, 256, 0, stream>>>(enc_in, emb, Xe);
  // encoder input gates for all timesteps: GXe = Xe @ w_ih_e^T + (b_ih_e + b_hh_e)
  k_gemm<1><<<dim3(16, 64), 256, 0, stream>>>(Xe, Wie, b_ih_e, b_hh_e, GXe, 8192, 2048, 512);
  // 16 independent per-batch recurrence groups x 16 blocks
  k_enc_r<<<256, 512, 0, stream>>>(GXe, w_hh_e, hexE, cT, hT, enc_out);
  k_gates0<<<256, 128, 0, stream>>>(dec_in, emb, hT, w_ih_d, w_hh_d, b_ih_d, b_hh_d, g0);
  k_dec_r<<<256, 512, 0, stream>>>(w_ih_d, w_hh_d, b_ih_d, b_hh_d, g0, hexD, cT, dec_h, dOutB);
  k_attn<<<128, 256, 0, stream>>>(dec_h, enc_out, dOutB);
  // logits = dec_out @ w_proj^T + b_proj
  k_gemm<0><<<dim3(250, 16), 256, 0, stream>>>(dOutB, Wp, b_proj, nullptr, out, 2048, 32000, 1024);
}